// Round 7
// baseline (263.825 us; speedup 1.0000x reference)
//
#include <hip/hip_runtime.h>
#include <hip/hip_fp16.h>

#define NPTS 500000
#define RPLANE 128
#define FDIM 32
#define PLSZ (RPLANE * RPLANE * FDIM)
#define NTILES 15625          // 500000 / 32
#define NWAVES 2048           // 256 blocks x 8 waves

typedef __bf16 bfx8 __attribute__((ext_vector_type(8)));
typedef float f32x4 __attribute__((ext_vector_type(4)));

__device__ __forceinline__ unsigned short f2bf(float f) {
    unsigned int u = __builtin_bit_cast(unsigned int, f);
    unsigned int r = (u + 0x7FFFu + ((u >> 16) & 1u)) >> 16;
    return (unsigned short)r;
}

__device__ __forceinline__ unsigned pk2(float a, float b) {
    return (unsigned)f2bf(a) | ((unsigned)f2bf(b) << 16);
}

__device__ __forceinline__ __half2 u2h(unsigned u) {
    return __builtin_bit_cast(__half2, u);
}

__device__ __forceinline__ bfx8 asfrag(uint4 v) {
    return __builtin_bit_cast(bfx8, v);
}

// D->act-frag conversion: from two packed D tiles (even e0,e1 / odd o0,o1),
// build one act frag (4 u32). a0/a1 are bpermute byte-addrs, sel = (lane>=32).
__device__ __forceinline__ uint4 convD(unsigned e0, unsigned e1, unsigned o0,
                                       unsigned o1, int a0, int a1, bool sel) {
    uint4 W;
    int x, y;
    x = __builtin_amdgcn_ds_bpermute(a0, (int)e0);
    y = __builtin_amdgcn_ds_bpermute(a0, (int)o0);
    W.x = (unsigned)(sel ? y : x);
    x = __builtin_amdgcn_ds_bpermute(a0, (int)e1);
    y = __builtin_amdgcn_ds_bpermute(a0, (int)o1);
    W.y = (unsigned)(sel ? y : x);
    x = __builtin_amdgcn_ds_bpermute(a1, (int)e0);
    y = __builtin_amdgcn_ds_bpermute(a1, (int)o0);
    W.z = (unsigned)(sel ? y : x);
    x = __builtin_amdgcn_ds_bpermute(a1, (int)e1);
    y = __builtin_amdgcn_ds_bpermute(a1, (int)o1);
    W.w = (unsigned)(sel ? y : x);
    return W;
}

// Repack weight mats to bf16 MFMA frags + planes to fp16.
// Frag block b = ct*(K/32)+ks, lane l, elem j: W[k=ks*32+(l>>4)*8+j][col=ct*16+(l&15)].
__global__ void prep_all(const float* __restrict__ wenc, const float* __restrict__ w1,
                         const float* __restrict__ w2, const float* __restrict__ spf,
                         const float* __restrict__ tpf,
                         unsigned short* __restrict__ wf, __half* __restrict__ ph) {
    const int WTOT = 86016;
    const int PTOT = 6 * PLSZ;
    const int total = WTOT + PTOT;
    for (int i = blockIdx.x * blockDim.x + threadIdx.x; i < total;
         i += gridDim.x * blockDim.x) {
        if (i < WTOT) {
            const float* W;
            unsigned short* dst;
            int K, Ncols, idx;
            if (i < 8192)       { W = wenc; K = 32;  Ncols = 256; idx = i;         dst = wf; }
            else if (i < 73728) { W = w1;   K = 256; Ncols = 256; idx = i - 8192;  dst = wf + 8192; }
            else                { W = w2;   K = 256; Ncols = 48;  idx = i - 73728; dst = wf + 73728; }
            int j = idx & 7;
            int l = (idx >> 3) & 63;
            int b = idx >> 9;
            int KS = K >> 5;
            int ct = b / KS;
            int ks = b - ct * KS;
            int k = ks * 32 + ((l >> 4) << 3) + j;
            int col = ct * 16 + (l & 15);
            dst[idx] = f2bf(W[(size_t)k * Ncols + col]);
        } else {
            int j = i - WTOT;
            float v = (j < 3 * PLSZ) ? spf[j] : tpf[j - 3 * PLSZ];
            ph[j] = __float2half(v);
        }
    }
}

// Latency-phase kernel: 1 thread/point. Does passthrough copies AND the
// 6-plane bilinear gather/product; writes the 32-feature vector in MFMA
// A-frag order into the out buffer's shs region (tile-bijective placement:
// ftile f's 1KB frag lives inside the 3KB out-slot of the same 16 points,
// consumed by mlp6 before it overwrites).
__global__ void gather_feat(const float* __restrict__ rays, const float* __restrict__ tme,
                            const float* __restrict__ rot, const float* __restrict__ h_e,
                            const __half* __restrict__ ph, float* __restrict__ out) {
    int p = blockIdx.x * blockDim.x + threadIdx.x;
    if (p >= NPTS) return;
    // passthrough
    float3 r3 = *(const float3*)(rays + 3 * p);
    out[3 * p + 0] = r3.x;
    out[3 * p + 1] = r3.y;
    out[3 * p + 2] = r3.z;
    float4 r4 = *(const float4*)(rot + 4 * p);
    *(float4*)(out + 3 * NPTS + 4 * p) = r4;
    out[7 * NPTS + p] = h_e[2 * p];

    const float inv = 0.625f;
    float xn = fminf(fmaxf(r3.x * inv, -1.f), 1.f) * 0.5f + 0.5f;
    float yn = fminf(fmaxf(r3.y * inv, -1.f), 1.f) * 0.5f + 0.5f;
    float zn = fminf(fmaxf(r3.z * inv, -1.f), 1.f) * 0.5f + 0.5f;
    float tt = fminf(fmaxf(tme[p], 0.f), 1.f);
    float c4[4] = {xn, yn, zn, tt};
    int i0[4];
    float fr[4];
#pragma unroll
    for (int cc = 0; cc < 4; ++cc) {
        float x = c4[cc] * 127.0f;
        float xf = fminf(floorf(x), 126.0f);
        i0[cc] = (int)xf;
        fr[cc] = x - xf;
    }
    const int uc[6] = {0, 0, 1, 0, 1, 2};
    const int vc[6] = {1, 2, 2, 3, 3, 3};
    __half2 g2[16];
#pragma unroll
    for (int pl = 0; pl < 6; ++pl) {
        int x0 = i0[uc[pl]], y0 = i0[vc[pl]];
        float fx = fr[uc[pl]], fy = fr[vc[pl]];
        const __half* base = ph + (size_t)pl * PLSZ + ((y0 * RPLANE + x0) << 5);
        const uint4* b00 = (const uint4*)base;
        const uint4* b01 = (const uint4*)(base + FDIM);
        const uint4* b10 = (const uint4*)(base + RPLANE * FDIM);
        const uint4* b11 = (const uint4*)(base + RPLANE * FDIM + FDIM);
        __half2 wa = __float2half2_rn((1.f - fx) * (1.f - fy));
        __half2 wb = __float2half2_rn(fx * (1.f - fy));
        __half2 wc = __float2half2_rn((1.f - fx) * fy);
        __half2 wd = __float2half2_rn(fx * fy);
#pragma unroll
        for (int q = 0; q < 4; ++q) {
            uint4 A = b00[q], B = b01[q], C = b10[q], D = b11[q];
            unsigned ua[4] = {A.x, A.y, A.z, A.w};
            unsigned ub[4] = {B.x, B.y, B.z, B.w};
            unsigned uccr[4] = {C.x, C.y, C.z, C.w};
            unsigned ud[4] = {D.x, D.y, D.z, D.w};
#pragma unroll
            for (int j = 0; j < 4; ++j) {
                __half2 r = __hmul2(u2h(ua[j]), wa);
                r = __hfma2(u2h(ub[j]), wb, r);
                r = __hfma2(u2h(uccr[j]), wc, r);
                r = __hfma2(u2h(ud[j]), wd, r);
                int i = q * 4 + j;
                g2[i] = (pl == 0) ? r : __hmul2(g2[i], r);
            }
        }
    }
    // write A-frag order: ftile f, lane l = g*16+c holds features 8g..8g+7 of point c
    int f = p >> 4, c = p & 15;
    char* fb = (char*)out + (size_t)NPTS * 32 + (size_t)f * 3072;
#pragma unroll
    for (int g = 0; g < 4; ++g) {
        float2 v0 = __half22float2(g2[4 * g + 0]);
        float2 v1 = __half22float2(g2[4 * g + 1]);
        float2 v2 = __half22float2(g2[4 * g + 2]);
        float2 v3 = __half22float2(g2[4 * g + 3]);
        uint4 av;
        av.x = pk2(v0.x, v0.y);
        av.y = pk2(v1.x, v1.y);
        av.z = pk2(v2.x, v2.y);
        av.w = pk2(v3.x, v3.y);
        *(uint4*)(fb + (g * 16 + c) * 16) = av;
    }
}

// Compute-phase kernel: pure MFMA MLP. 8 waves/block share w1+w2 frags in LDS;
// each wave streams ~8 tiles of 32 points: read act frags, 336 MFMA, store.
__global__ __launch_bounds__(512, 1) void mlp6(
    const float* __restrict__ shs, const unsigned short* __restrict__ wf,
    const float* __restrict__ benc, const float* __restrict__ b1v,
    const float* __restrict__ b2v, float* __restrict__ out) {
    __shared__ unsigned short wlds[77824];   // w1 frags [0,65536) + w2 frags [65536,77824)
    const int tid = threadIdx.x;
    const int wid = tid >> 6;
    const int lane = tid & 63;
#pragma unroll
    for (int i = tid * 8; i < 77824; i += 512 * 8)
        *(uint4*)&wlds[i] = *(const uint4*)(wf + 8192 + i);
    __syncthreads();

    const int g = lane >> 4;
    const int c = lane & 15;
    const int a0 = 4 * (32 * (g & 1) + c);
    const int a1 = a0 + 64;
    const bool sel = (g >> 1) != 0;
    const char* fb = (const char*)out + (size_t)NPTS * 32;
    const int w = blockIdx.x * 8 + wid;

    for (int it = 0; it < 8; ++it) {
        int tile = w + NWAVES * it;
        if (tile >= NTILES) break;
        const int p0 = tile * 32;

        bfx8 act1[2];
        act1[0] = asfrag(*(const uint4*)(fb + (size_t)(2 * tile + 0) * 3072 + lane * 16));
        act1[1] = asfrag(*(const uint4*)(fb + (size_t)(2 * tile + 1) * 3072 + lane * 16));

        // ---- layer 1: wenc frags from global (L1-hot); convert -> act2 ----
        uint4 act2[2][8];
        {
            unsigned stE[2][2];
#pragma unroll
            for (int ct = 0; ct < 16; ++ct) {
                uint4 cur = *(const uint4*)(wf + (size_t)ct * 512 + lane * 8);
                float4 b4 = *(const float4*)(benc + 16 * ct + 4 * g);
                float bb[4] = {b4.x, b4.y, b4.z, b4.w};
#pragma unroll
                for (int pt = 0; pt < 2; ++pt) {
                    f32x4 z = {0.f, 0.f, 0.f, 0.f};
                    f32x4 d = __builtin_amdgcn_mfma_f32_16x16x32_bf16(asfrag(cur), act1[pt], z, 0, 0, 0);
                    float v0 = fmaxf(d[0] + bb[0], 0.f);
                    float v1 = fmaxf(d[1] + bb[1], 0.f);
                    float v2 = fmaxf(d[2] + bb[2], 0.f);
                    float v3 = fmaxf(d[3] + bb[3], 0.f);
                    unsigned Q0 = pk2(v0, v1), Q1 = pk2(v2, v3);
                    if ((ct & 1) == 0) {
                        stE[pt][0] = Q0; stE[pt][1] = Q1;
                    } else {
                        act2[pt][ct >> 1] = convD(stE[pt][0], stE[pt][1], Q0, Q1, a0, a1, sel);
                    }
                }
            }
        }

        // ---- layer 2: w1 frags from LDS; convert -> act3 ----
        uint4 act3[2][8];
        {
            unsigned stE[2][2];
#pragma unroll
            for (int ct = 0; ct < 16; ++ct) {
                uint4 wv[8];
#pragma unroll
                for (int ks = 0; ks < 8; ++ks)
                    wv[ks] = *(const uint4*)&wlds[(ct * 8 + ks) * 512 + lane * 8];
                float4 b4 = *(const float4*)(b1v + 16 * ct + 4 * g);
                float bb[4] = {b4.x, b4.y, b4.z, b4.w};
#pragma unroll
                for (int pt = 0; pt < 2; ++pt) {
                    f32x4 acc = {0.f, 0.f, 0.f, 0.f};
#pragma unroll
                    for (int ks = 0; ks < 8; ++ks)
                        acc = __builtin_amdgcn_mfma_f32_16x16x32_bf16(asfrag(wv[ks]), asfrag(act2[pt][ks]), acc, 0, 0, 0);
                    float v0 = fmaxf(acc[0] + bb[0], 0.f);
                    float v1 = fmaxf(acc[1] + bb[1], 0.f);
                    float v2 = fmaxf(acc[2] + bb[2], 0.f);
                    float v3 = fmaxf(acc[3] + bb[3], 0.f);
                    unsigned Q0 = pk2(v0, v1), Q1 = pk2(v2, v3);
                    if ((ct & 1) == 0) {
                        stE[pt][0] = Q0; stE[pt][1] = Q1;
                    } else {
                        act3[pt][ct >> 1] = convD(stE[pt][0], stE[pt][1], Q0, Q1, a0, a1, sel);
                    }
                }
            }
        }

        // ---- layer 3: w2 frags from LDS; D[pt][outcol]; + b2 + shs -> out ----
        {
#pragma unroll
            for (int ct = 0; ct < 3; ++ct) {
                uint4 wl[8];
#pragma unroll
                for (int ks = 0; ks < 8; ++ks)
                    wl[ks] = *(const uint4*)&wlds[65536 + (ct * 8 + ks) * 512 + lane * 8];
                float bias = b2v[16 * ct + c];
#pragma unroll
                for (int pt = 0; pt < 2; ++pt) {
                    f32x4 acc = {0.f, 0.f, 0.f, 0.f};
#pragma unroll
                    for (int ks = 0; ks < 8; ++ks)
                        acc = __builtin_amdgcn_mfma_f32_16x16x32_bf16(asfrag(act3[pt][ks]), asfrag(wl[ks]), acc, 0, 0, 0);
#pragma unroll
                    for (int r = 0; r < 4; ++r) {
                        int p = p0 + pt * 16 + 4 * g + r;
                        size_t idx = (size_t)p * 48 + 16 * ct + c;
                        out[(size_t)NPTS * 8 + idx] = shs[idx] + acc[r] + bias;
                    }
                }
            }
        }
    }
}

extern "C" void kernel_launch(void* const* d_in, const int* in_sizes, int n_in,
                              void* d_out, int out_size, void* d_ws, size_t ws_size,
                              hipStream_t stream) {
    const float* rays = (const float*)d_in[0];
    const float* rot  = (const float*)d_in[1];
    const float* shs  = (const float*)d_in[3];
    const float* tme  = (const float*)d_in[5];
    const float* h_e  = (const float*)d_in[6];
    const float* spf  = (const float*)d_in[7];
    const float* tpf  = (const float*)d_in[8];
    const float* wenc = (const float*)d_in[9];
    const float* benc = (const float*)d_in[10];
    const float* w1   = (const float*)d_in[11];
    const float* b1v  = (const float*)d_in[12];
    const float* w2   = (const float*)d_in[13];
    const float* b2v  = (const float*)d_in[14];
    float* out = (float*)d_out;
    unsigned short* wf = (unsigned short*)d_ws;    // 86016 shorts of weight frags
    __half* ph = (__half*)(wf + 86016);            // 6*PLSZ fp16 plane cache (~6.3 MB)

    prep_all<<<3408, 256, 0, stream>>>(wenc, w1, w2, spf, tpf, wf, ph);
    gather_feat<<<(NPTS + 255) / 256, 256, 0, stream>>>(rays, tme, rot, h_e, ph, out);
    mlp6<<<256, 512, 0, stream>>>(shs, wf, benc, b1v, b2v, out);
}